// Round 11
// baseline (118.348 us; speedup 1.0000x reference)
//
#include <hip/hip_runtime.h>
#include <math.h>

#define NTH 512                     // 8 waves per block
#define KP 264                      // LDS row stride (ushorts), padded
#define SPB 16                      // samples per block (fills M=16 MFMA tiles)
#define OFF_W2 0                    // 4 tiles x 4 ksteps
#define OFF_V1 16384                // 16 x 2
#define OFF_V2 49152                // 16 x 8
#define OFF_V3 180224               // 4 x 8
#define WS_USHORTS 212992
#define MFMA16 __builtin_amdgcn_mfma_f32_16x16x32_bf16

typedef __attribute__((ext_vector_type(8))) short s16x8;
typedef __attribute__((ext_vector_type(8))) unsigned short u16x8;
typedef __attribute__((ext_vector_type(4))) float f32x4;

__device__ __forceinline__ float waveSum(float v) {
#pragma unroll
  for (int off = 32; off; off >>= 1) v += __shfl_xor(v, off, 64);
  return v;
}

__device__ __forceinline__ float siluf(float x) { return x / (1.0f + expf(-x)); }

// Round fp32 -> bf16 (RNE), return bits.
__device__ __forceinline__ unsigned short bround(float x) {
  unsigned u = __float_as_uint(x);
  return (unsigned short)((u + 0x7FFFu + ((u >> 16) & 1u)) >> 16);
}

// Split fp32 into bf16 hi + bf16 lo (round-to-nearest-even).
__device__ __forceinline__ void bsplit(float x, unsigned short& h, unsigned short& l) {
  unsigned u = __float_as_uint(x);
  unsigned hb = (u + 0x7FFFu + ((u >> 16) & 1u)) >> 16;
  float hf = __uint_as_float(hb << 16);
  float lf = x - hf;
  unsigned ul = __float_as_uint(lf);
  unsigned lb = (ul + 0x7FFFu + ((ul >> 16) & 1u)) >> 16;
  h = (unsigned short)hb; l = (unsigned short)lb;
}

// permSum is symmetric in (se0..se4): it sums over all 120 orderings.
__device__ __forceinline__ float permSum(const float se0, const float se1,
                                         const float se2, const float se3,
                                         const float se4, float Z, int lane) {
  float psum = 0.0f;
#pragma unroll
  for (int pp = 0; pp < 2; ++pp) {
    int p = lane + pp * 64;
    if (p < 120) {
      int rem = p;
      unsigned avail = 0x43210u;
      float c = 0.0f;
      float prod = Z;
#pragma unroll
      for (int j = 0; j < 4; ++j) {
        const int fct = (j == 0) ? 24 : (j == 1) ? 6 : (j == 2) ? 2 : 1;
        int q = rem / fct; rem -= q * fct;
        int sh = q * 4;
        int dg = (avail >> sh) & 0xF;
        avail = (avail & ((1u << sh) - 1u)) | ((avail >> (sh + 4)) << sh);
        float ev = (dg == 0) ? se0 : (dg == 1) ? se1 : (dg == 2) ? se2
                 : (dg == 3) ? se3 : se4;
        c += ev;
        prod *= (Z - c);
      }
      psum += 1.0f / prod;
    }
  }
  return psum;
}

// Rank-based Gumbel top-5 + exact PL log-prob; g = precomputed perturbation.
// Tie-break (equal v -> lower index) matches jax.lax.top_k. sValsRow/sSelERow
// are per-sample LDS rows; same-wave DS ordering makes this barrier-free.
__device__ __forceinline__ float selectAndPL(float lv, float ev, float Z,
                                             float g,
                                             float* __restrict__ gout,
                                             int lane,
                                             float* __restrict__ sValsRow,
                                             float* __restrict__ sSelERow,
                                             int* __restrict__ selIdxRow) {
  float v = lv + g;
  sValsRow[lane] = v;
  int rank = 0;
#pragma unroll
  for (int j = 0; j < 16; ++j) {
    float4 w = *(const float4*)&sValsRow[j * 4];
    int base = j * 4;
    rank += (w.x > v || (w.x == v && base + 0 < lane)) ? 1 : 0;
    rank += (w.y > v || (w.y == v && base + 1 < lane)) ? 1 : 0;
    rank += (w.z > v || (w.z == v && base + 2 < lane)) ? 1 : 0;
    rank += (w.w > v || (w.w == v && base + 3 < lane)) ? 1 : 0;
  }
  bool sel = rank < 5;
  gout[lane] = sel ? 1.0f : 0.0f;
  if (sel) {
    sSelERow[rank] = ev;
    if (selIdxRow) selIdxRow[rank] = lane;
  }
  float sl = waveSum(sel ? lv : 0.0f);
  float se0 = sSelERow[0], se1 = sSelERow[1], se2 = sSelERow[2],
        se3 = sSelERow[3], se4 = sSelERow[4];
  float S = waveSum(permSum(se0, se1, se2, se3, se4, Z, lane));
  return sl + logf(S);
}

//============ Prep: tile + split weights into fragment order ============
__global__ __launch_bounds__(256)
void pcf_prep(const float* __restrict__ W2, const float* __restrict__ V1,
              const float* __restrict__ V2, const float* __restrict__ V3,
              unsigned short* __restrict__ ws)
{
  int tid = blockIdx.x * 256 + threadIdx.x;
  const float* src; int N, Ks, dstoff, r;
  if (tid < 1024)       { src = W2;            N = 64;  Ks = 4; dstoff = OFF_W2; r = tid; }
  else if (tid < 3072)  { src = V1 + 64 * 256; N = 256; Ks = 2; dstoff = OFF_V1; r = tid - 1024; }
  else if (tid < 11264) { src = V2;            N = 256; Ks = 8; dstoff = OFF_V2; r = tid - 3072; }
  else                  { src = V3;            N = 64;  Ks = 8; dstoff = OFF_V3; r = tid - 11264; }
  int lane = r & 63, ts = r >> 6;
  int ks = ts % Ks, ct = ts / Ks;
  int n = ct * 16 + (lane & 15);
  int k0 = ks * 32 + (lane >> 4) * 8;
  u16x8 hv, lv;
#pragma unroll
  for (int j = 0; j < 8; ++j) {
    float x = src[(size_t)(k0 + j) * N + n];
    unsigned short h, l;
    bsplit(x, h, l);
    hv[j] = h; lv[j] = l;
  }
  unsigned short* dst = ws + dstoff + (size_t)ts * 1024 + lane * 8;
  *(u16x8*)dst = hv;
  *(u16x8*)(dst + 512) = lv;
}

//============ Main: 16 samples/block, 8 waves, MFMA (act hi, wt hi+lo) =====
__global__ __launch_bounds__(NTH, 8)
void pcf_mfma(const float* __restrict__ ua, const float* __restrict__ ub,
              const float* __restrict__ alog, const float* __restrict__ W1,
              const float* __restrict__ b1, const float* __restrict__ b2,
              const float* __restrict__ c1, const float* __restrict__ c2,
              const float* __restrict__ c3,
              const unsigned short* __restrict__ wt, float* __restrict__ out)
{
  __shared__ unsigned short sAhi[16 * KP];   // 8448 B
  __shared__ unsigned short sBhi[16 * KP];   // 8448 B
  __shared__ float sBL[SPB * 64];            // 4096 B
  __shared__ float sVals[SPB * 64];          // 4096 B  rank scratch (per sample)
  __shared__ float sSelE[SPB * 8];           // 512 B   selected exps (per sample)
  __shared__ int   sSelA[SPB * 5];
  __shared__ float sLpA[SPB];

  const int t    = threadIdx.x;
  const int lane = t & 63;
  const int wv   = t >> 6;                   // 0..7
  const int ln15 = lane & 15;
  const int quad = lane >> 4;
  const int bbase = blockIdx.x * SPB;

  //===== Prefetch + hoist: beta Gumbel perturbations (used after 5 barriers)
  float gb[2];
#pragma unroll
  for (int si = 0; si < 2; ++si) {
    int b = bbase + wv * 2 + si;
    float u = ub[(size_t)b * 64 + lane];
    gb[si] = -logf(-logf(fmaxf(u, 1e-10f)));
  }

  //===== Phase A: alpha top-5 + PL (2 samples per wave, ILP-unrolled) =====
  {
    float la = alog[lane];
    float ea = expf(la);
    float Za = waveSum(ea);
#pragma unroll
    for (int si = 0; si < 2; ++si) {
      int s = wv * 2 + si;
      int b = bbase + s;
      float u = ua[(size_t)b * 64 + lane];
      float ga = -logf(-logf(fmaxf(u, 1e-10f)));
      float lp = selectAndPL(la, ea, Za, ga, out + (size_t)b * 128, lane,
                             &sVals[s * 64], &sSelE[s * 8], &sSelA[s * 5]);
      if (lane == 0) sLpA[s] = lp;
    }
  }
  __syncthreads();

  //===== Phase H: h[s][0..127] = silu(b1 + sum 5 W1 rows) -> sAhi =====
  {
    int j = lane * 2;           // cols j, j+1
    float2 bv = *(const float2*)(b1 + j);
#pragma unroll
    for (int si = 0; si < 2; ++si) {
      int s = wv * 2 + si;
      const int rows[5] = { sSelA[s * 5 + 0], sSelA[s * 5 + 1], sSelA[s * 5 + 2],
                            sSelA[s * 5 + 3], sSelA[s * 5 + 4] };
      float2 a = bv;
#pragma unroll
      for (int r = 0; r < 5; ++r) {
        float2 w = *(const float2*)(W1 + (size_t)rows[r] * 128 + j);
        a.x += w.x; a.y += w.y;
      }
      unsigned h0 = bround(siluf(a.x));
      unsigned h1 = bround(siluf(a.y));
      *(unsigned*)&sAhi[s * KP + j] = h0 | (h1 << 16);
    }
  }
  __syncthreads();

  //===== GEMM1: ctx(16x64) = h @ W2 + b2  (K=128, waves 0-3) =====
  if (wv < 4) {
    f32x4 acc = {0.f, 0.f, 0.f, 0.f};
#pragma unroll
    for (int ks = 0; ks < 4; ++ks) {
      int ko = ks * 32 + quad * 8;
      s16x8 ah = *(const s16x8*)&sAhi[ln15 * KP + ko];
      const unsigned short* tsb = wt + OFF_W2 + (size_t)(wv * 4 + ks) * 1024;
      s16x8 bh = ((const s16x8*)tsb)[lane];
      s16x8 bl = ((const s16x8*)(tsb + 512))[lane];
      acc = MFMA16(ah, bh, acc, 0, 0, 0);
      acc = MFMA16(ah, bl, acc, 0, 0, 0);
    }
    int col = wv * 16 + ln15;
    float bias = b2[col];
#pragma unroll
    for (int r = 0; r < 4; ++r)
      sBhi[(quad * 4 + r) * KP + col] = bround(acc[r] + bias);
  }
  __syncthreads();

  //===== GEMM2: z1(16x256) = silu(ctx @ V1[64:,:] + c1)  (K=64, 2 tiles/wave) =====
  {
    f32x4 acc[2];
#pragma unroll
    for (int i = 0; i < 2; ++i) acc[i] = (f32x4){0.f, 0.f, 0.f, 0.f};
#pragma unroll
    for (int ks = 0; ks < 2; ++ks) {
      int ko = ks * 32 + quad * 8;
      s16x8 ah = *(const s16x8*)&sBhi[ln15 * KP + ko];
#pragma unroll
      for (int i = 0; i < 2; ++i) {
        const unsigned short* tsb = wt + OFF_V1 + (size_t)((wv * 2 + i) * 2 + ks) * 1024;
        s16x8 bh = ((const s16x8*)tsb)[lane];
        s16x8 bl = ((const s16x8*)(tsb + 512))[lane];
        acc[i] = MFMA16(ah, bh, acc[i], 0, 0, 0);
        acc[i] = MFMA16(ah, bl, acc[i], 0, 0, 0);
      }
    }
#pragma unroll
    for (int i = 0; i < 2; ++i) {
      int col = (wv * 2 + i) * 16 + ln15;
      float bias = c1[col];
#pragma unroll
      for (int r = 0; r < 4; ++r)
        sAhi[(quad * 4 + r) * KP + col] = bround(siluf(acc[i][r] + bias));
    }
  }
  __syncthreads();

  //===== GEMM3: z2(16x256) = silu(z1 @ V2 + c2)  (K=256, 2 tiles/wave) =====
  {
    f32x4 acc[2];
#pragma unroll
    for (int i = 0; i < 2; ++i) acc[i] = (f32x4){0.f, 0.f, 0.f, 0.f};
#pragma unroll 4
    for (int ks = 0; ks < 8; ++ks) {
      int ko = ks * 32 + quad * 8;
      s16x8 ah = *(const s16x8*)&sAhi[ln15 * KP + ko];
#pragma unroll
      for (int i = 0; i < 2; ++i) {
        const unsigned short* tsb = wt + OFF_V2 + (size_t)((wv * 2 + i) * 8 + ks) * 1024;
        s16x8 bh = ((const s16x8*)tsb)[lane];
        s16x8 bl = ((const s16x8*)(tsb + 512))[lane];
        acc[i] = MFMA16(ah, bh, acc[i], 0, 0, 0);
        acc[i] = MFMA16(ah, bl, acc[i], 0, 0, 0);
      }
    }
#pragma unroll
    for (int i = 0; i < 2; ++i) {
      int col = (wv * 2 + i) * 16 + ln15;
      float bias = c2[col];
#pragma unroll
      for (int r = 0; r < 4; ++r)
        sBhi[(quad * 4 + r) * KP + col] = bround(siluf(acc[i][r] + bias));
    }
  }
  __syncthreads();

  //===== GEMM4: beta_logits(16x64) = z2 @ V3 + c3  (K=256, waves 0-3) =====
  if (wv < 4) {
    f32x4 acc = {0.f, 0.f, 0.f, 0.f};
#pragma unroll
    for (int ks = 0; ks < 8; ++ks) {
      int ko = ks * 32 + quad * 8;
      s16x8 ah = *(const s16x8*)&sBhi[ln15 * KP + ko];
      const unsigned short* tsb = wt + OFF_V3 + (size_t)(wv * 8 + ks) * 1024;
      s16x8 bh = ((const s16x8*)tsb)[lane];
      s16x8 bl = ((const s16x8*)(tsb + 512))[lane];
      acc = MFMA16(ah, bh, acc, 0, 0, 0);
      acc = MFMA16(ah, bl, acc, 0, 0, 0);
    }
    int col = wv * 16 + ln15;
    float bias = c3[col];
#pragma unroll
    for (int r = 0; r < 4; ++r)
      sBL[(quad * 4 + r) * 64 + col] = acc[r] + bias;
  }
  __syncthreads();

  //===== Phase B: beta top-5 + PL (2 samples per wave, hoisted Gumbel) =====
  {
#pragma unroll
    for (int si = 0; si < 2; ++si) {
      int s = wv * 2 + si;
      int b = bbase + s;
      float blv = sBL[s * 64 + lane];
      float eb = expf(blv);
      float Zb = waveSum(eb);
      float lp = selectAndPL(blv, eb, Zb, gb[si],
                             out + (size_t)b * 128 + 64, lane,
                             &sVals[s * 64], &sSelE[s * 8], nullptr);
      if (lane == 0)
        out[(size_t)8192 * 128 + b] = sLpA[s] + lp;
    }
  }
}

//================= Fallback (R4-style kernel, no ws needed) =================
#define SPB4 4
__global__ __launch_bounds__(256, 8)
void pcf_small(const float* __restrict__ ua, const float* __restrict__ ub,
               const float* __restrict__ alog, const float* __restrict__ W1,
               const float* __restrict__ b1, const float* __restrict__ W2,
               const float* __restrict__ b2, const float* __restrict__ V1,
               const float* __restrict__ c1, const float* __restrict__ V2,
               const float* __restrict__ c2, const float* __restrict__ V3,
               const float* __restrict__ c3, float* __restrict__ out)
{
  __shared__ float sA[SPB4 * 256];
  __shared__ float sB[SPB4 * 256];
  __shared__ float sP[4 * 256];
  __shared__ float sVals[4 * 64];
  __shared__ float sSelE[4 * 8];
  __shared__ int   sSelA[SPB4 * 5];
  __shared__ float sLpA[SPB4];

  const int t    = threadIdx.x;
  const int lane = t & 63;
  const int wv   = t >> 6;
  const int bbase = blockIdx.x * SPB4;

  float* sValsRow = &sVals[wv * 64];
  float* sSelERow = &sSelE[wv * 8];

  {
    float la = alog[lane];
    float ea = expf(la);
    float Za = waveSum(ea);
    int b = bbase + wv;
    float u = ua[(size_t)b * 64 + lane];
    float g = -logf(-logf(fmaxf(u, 1e-10f)));
    float lp = selectAndPL(la, ea, Za, g, out + (size_t)b * 128, lane,
                           sValsRow, sSelERow, &sSelA[wv * 5]);
    if (lane == 0) sLpA[wv] = lp;
  }
  __syncthreads();
  {
    int s = wv;
    int i0 = sSelA[s * 5 + 0], i1 = sSelA[s * 5 + 1], i2 = sSelA[s * 5 + 2];
    int i3 = sSelA[s * 5 + 3], i4 = sSelA[s * 5 + 4];
#pragma unroll
    for (int jh = 0; jh < 2; ++jh) {
      int j = lane + jh * 64;
      float acc = b1[j] + W1[i0 * 128 + j] + W1[i1 * 128 + j]
                + W1[i2 * 128 + j] + W1[i3 * 128 + j] + W1[i4 * 128 + j];
      sA[s * 128 + j] = siluf(acc);
    }
  }
  __syncthreads();
  {
    float acc[SPB4] = {};
    const int kb = 32 * wv;
#pragma unroll 2
    for (int m = 0; m < 8; ++m) {
      int k0 = kb + 4 * m;
      float w0 = W2[(k0 + 0) * 64 + lane];
      float w1 = W2[(k0 + 1) * 64 + lane];
      float w2 = W2[(k0 + 2) * 64 + lane];
      float w3 = W2[(k0 + 3) * 64 + lane];
#pragma unroll
      for (int s = 0; s < SPB4; ++s) {
        float4 x = *(float4*)&sA[s * 128 + k0];
        acc[s] += x.x * w0 + x.y * w1 + x.z * w2 + x.w * w3;
      }
    }
#pragma unroll
    for (int s = 0; s < SPB4; ++s) sP[wv * 256 + s * 64 + lane] = acc[s];
  }
  __syncthreads();
  {
    int o = t;
    float v = b2[o & 63] + sP[o] + sP[256 + o] + sP[512 + o] + sP[768 + o];
    sB[o] = v;
  }
  __syncthreads();
  {
    const int c = 64 * wv + lane;
    float acc[SPB4];
    float cb = c1[c];
#pragma unroll
    for (int s = 0; s < SPB4; ++s) acc[s] = cb;
    const float* wp = V1 + (size_t)64 * 256 + c;
#pragma unroll 4
    for (int m = 0; m < 16; ++m) {
      int k0 = 4 * m;
      float w0 = wp[(k0 + 0) * 256];
      float w1 = wp[(k0 + 1) * 256];
      float w2 = wp[(k0 + 2) * 256];
      float w3 = wp[(k0 + 3) * 256];
#pragma unroll
      for (int s = 0; s < SPB4; ++s) {
        float4 x = *(float4*)&sB[s * 64 + k0];
        acc[s] += x.x * w0 + x.y * w1 + x.z * w2 + x.w * w3;
      }
    }
#pragma unroll
    for (int s = 0; s < SPB4; ++s) sA[s * 256 + c] = siluf(acc[s]);
  }
  __syncthreads();
  {
    const int c = 64 * wv + lane;
    float acc[SPB4];
    float cb = c2[c];
#pragma unroll
    for (int s = 0; s < SPB4; ++s) acc[s] = cb;
    const float* wp = V2 + c;
#pragma unroll 4
    for (int m = 0; m < 64; ++m) {
      int k0 = 4 * m;
      float w0 = wp[(size_t)(k0 + 0) * 256];
      float w1 = wp[(size_t)(k0 + 1) * 256];
      float w2 = wp[(size_t)(k0 + 2) * 256];
      float w3 = wp[(size_t)(k0 + 3) * 256];
#pragma unroll
      for (int s = 0; s < SPB4; ++s) {
        float4 x = *(float4*)&sA[s * 256 + k0];
        acc[s] += x.x * w0 + x.y * w1 + x.z * w2 + x.w * w3;
      }
    }
#pragma unroll
    for (int s = 0; s < SPB4; ++s) sB[s * 256 + c] = siluf(acc[s]);
  }
  __syncthreads();
  {
    float acc[SPB4] = {};
    const int kb = 64 * wv;
#pragma unroll 4
    for (int m = 0; m < 16; ++m) {
      int k0 = kb + 4 * m;
      float w0 = V3[(k0 + 0) * 64 + lane];
      float w1 = V3[(k0 + 1) * 64 + lane];
      float w2 = V3[(k0 + 2) * 64 + lane];
      float w3 = V3[(k0 + 3) * 64 + lane];
#pragma unroll
      for (int s = 0; s < SPB4; ++s) {
        float4 x = *(float4*)&sB[s * 256 + k0];
        acc[s] += x.x * w0 + x.y * w1 + x.z * w2 + x.w * w3;
      }
    }
#pragma unroll
    for (int s = 0; s < SPB4; ++s) sP[wv * 256 + s * 64 + lane] = acc[s];
  }
  __syncthreads();
  {
    int b = bbase + wv;
    float blv = c3[lane] + sP[wv * 64 + lane] + sP[256 + wv * 64 + lane]
              + sP[512 + wv * 64 + lane] + sP[768 + wv * 64 + lane];
    float eb = expf(blv);
    float Zb = waveSum(eb);
    float u = ub[(size_t)b * 64 + lane];
    float g = -logf(-logf(fmaxf(u, 1e-10f)));
    float lp = selectAndPL(blv, eb, Zb, g, out + (size_t)b * 128 + 64, lane,
                           sValsRow, sSelERow, nullptr);
    if (lane == 0)
      out[(size_t)8192 * 128 + b] = sLpA[wv] + lp;
  }
}

extern "C" void kernel_launch(void* const* d_in, const int* in_sizes, int n_in,
                              void* d_out, int out_size, void* d_ws, size_t ws_size,
                              hipStream_t stream) {
  const float* ua   = (const float*)d_in[0];
  const float* ub   = (const float*)d_in[1];
  const float* alog = (const float*)d_in[2];
  const float* W1   = (const float*)d_in[3];
  const float* b1   = (const float*)d_in[4];
  const float* W2   = (const float*)d_in[5];
  const float* b2   = (const float*)d_in[6];
  const float* V1   = (const float*)d_in[7];
  const float* c1   = (const float*)d_in[8];
  const float* V2   = (const float*)d_in[9];
  const float* c2   = (const float*)d_in[10];
  const float* V3   = (const float*)d_in[11];
  const float* c3   = (const float*)d_in[12];
  float* out = (float*)d_out;

  if (ws_size >= (size_t)WS_USHORTS * 2) {
    unsigned short* wt = (unsigned short*)d_ws;
    pcf_prep<<<dim3(52), dim3(256), 0, stream>>>(W2, V1, V2, V3, wt);
    pcf_mfma<<<dim3(8192 / SPB), dim3(NTH), 0, stream>>>(
        ua, ub, alog, W1, b1, b2, c1, c2, c3, wt, out);
  } else {
    pcf_small<<<dim3(8192 / SPB4), dim3(256), 0, stream>>>(
        ua, ub, alog, W1, b1, W2, b2, V1, c1, V2, c2, V3, c3, out);
  }
}

// Round 12
// 105.995 us; speedup vs baseline: 1.1165x; 1.1165x over previous
//
#include <hip/hip_runtime.h>
#include <math.h>

#define NTH 1024                    // 16 waves per block
#define KP 264                      // LDS row stride (ushorts), padded
#define SPB 16                      // samples per block (fills M=16 MFMA tiles)
#define OFF_W2 0                    // 4 tiles x 4 ksteps
#define OFF_V1 16384                // 16 x 2
#define OFF_V2 49152                // 16 x 8
#define OFF_V3 180224               // 4 x 8
#define WS_USHORTS 212992
#define MFMA16 __builtin_amdgcn_mfma_f32_16x16x32_bf16

typedef __attribute__((ext_vector_type(8))) short s16x8;
typedef __attribute__((ext_vector_type(8))) unsigned short u16x8;
typedef __attribute__((ext_vector_type(4))) float f32x4;

__device__ __forceinline__ float waveSum(float v) {
#pragma unroll
  for (int off = 32; off; off >>= 1) v += __shfl_xor(v, off, 64);
  return v;
}

__device__ __forceinline__ float siluf(float x) { return x / (1.0f + expf(-x)); }

// Round fp32 -> bf16 (RNE), return bits.
__device__ __forceinline__ unsigned short bround(float x) {
  unsigned u = __float_as_uint(x);
  return (unsigned short)((u + 0x7FFFu + ((u >> 16) & 1u)) >> 16);
}

// Split fp32 into bf16 hi + bf16 lo (round-to-nearest-even).
__device__ __forceinline__ void bsplit(float x, unsigned short& h, unsigned short& l) {
  unsigned u = __float_as_uint(x);
  unsigned hb = (u + 0x7FFFu + ((u >> 16) & 1u)) >> 16;
  float hf = __uint_as_float(hb << 16);
  float lf = x - hf;
  unsigned ul = __float_as_uint(lf);
  unsigned lb = (ul + 0x7FFFu + ((ul >> 16) & 1u)) >> 16;
  h = (unsigned short)hb; l = (unsigned short)lb;
}

// permSum is symmetric in (se0..se4): it sums over all 120 orderings.
__device__ __forceinline__ float permSum(const float se0, const float se1,
                                         const float se2, const float se3,
                                         const float se4, float Z, int lane) {
  float psum = 0.0f;
#pragma unroll
  for (int pp = 0; pp < 2; ++pp) {
    int p = lane + pp * 64;
    if (p < 120) {
      int rem = p;
      unsigned avail = 0x43210u;
      float c = 0.0f;
      float prod = Z;
#pragma unroll
      for (int j = 0; j < 4; ++j) {
        const int fct = (j == 0) ? 24 : (j == 1) ? 6 : (j == 2) ? 2 : 1;
        int q = rem / fct; rem -= q * fct;
        int sh = q * 4;
        int dg = (avail >> sh) & 0xF;
        avail = (avail & ((1u << sh) - 1u)) | ((avail >> (sh + 4)) << sh);
        float ev = (dg == 0) ? se0 : (dg == 1) ? se1 : (dg == 2) ? se2
                 : (dg == 3) ? se3 : se4;
        c += ev;
        prod *= (Z - c);
      }
      psum += 1.0f / prod;
    }
  }
  return psum;
}

// Rank-based Gumbel top-5 + exact PL log-prob; g = precomputed perturbation.
// Tie-break (equal v -> lower index) matches jax.lax.top_k. sValsRow/sSelERow
// are per-sample LDS rows; same-wave DS ordering makes this barrier-free.
__device__ __forceinline__ float selectAndPL(float lv, float ev, float Z,
                                             float g,
                                             float* __restrict__ gout,
                                             int lane,
                                             float* __restrict__ sValsRow,
                                             float* __restrict__ sSelERow,
                                             int* __restrict__ selIdxRow) {
  float v = lv + g;
  sValsRow[lane] = v;
  int rank = 0;
#pragma unroll
  for (int j = 0; j < 16; ++j) {
    float4 w = *(const float4*)&sValsRow[j * 4];
    int base = j * 4;
    rank += (w.x > v || (w.x == v && base + 0 < lane)) ? 1 : 0;
    rank += (w.y > v || (w.y == v && base + 1 < lane)) ? 1 : 0;
    rank += (w.z > v || (w.z == v && base + 2 < lane)) ? 1 : 0;
    rank += (w.w > v || (w.w == v && base + 3 < lane)) ? 1 : 0;
  }
  bool sel = rank < 5;
  gout[lane] = sel ? 1.0f : 0.0f;
  if (sel) {
    sSelERow[rank] = ev;
    if (selIdxRow) selIdxRow[rank] = lane;
  }
  float sl = waveSum(sel ? lv : 0.0f);
  float se0 = sSelERow[0], se1 = sSelERow[1], se2 = sSelERow[2],
        se3 = sSelERow[3], se4 = sSelERow[4];
  float S = waveSum(permSum(se0, se1, se2, se3, se4, Z, lane));
  return sl + logf(S);
}

//============ Prep: tile + split weights into fragment order ============
__global__ __launch_bounds__(256)
void pcf_prep(const float* __restrict__ W2, const float* __restrict__ V1,
              const float* __restrict__ V2, const float* __restrict__ V3,
              unsigned short* __restrict__ ws)
{
  int tid = blockIdx.x * 256 + threadIdx.x;
  const float* src; int N, Ks, dstoff, r;
  if (tid < 1024)       { src = W2;            N = 64;  Ks = 4; dstoff = OFF_W2; r = tid; }
  else if (tid < 3072)  { src = V1 + 64 * 256; N = 256; Ks = 2; dstoff = OFF_V1; r = tid - 1024; }
  else if (tid < 11264) { src = V2;            N = 256; Ks = 8; dstoff = OFF_V2; r = tid - 3072; }
  else                  { src = V3;            N = 64;  Ks = 8; dstoff = OFF_V3; r = tid - 11264; }
  int lane = r & 63, ts = r >> 6;
  int ks = ts % Ks, ct = ts / Ks;
  int n = ct * 16 + (lane & 15);
  int k0 = ks * 32 + (lane >> 4) * 8;
  u16x8 hv, lv;
#pragma unroll
  for (int j = 0; j < 8; ++j) {
    float x = src[(size_t)(k0 + j) * N + n];
    unsigned short h, l;
    bsplit(x, h, l);
    hv[j] = h; lv[j] = l;
  }
  unsigned short* dst = ws + dstoff + (size_t)ts * 1024 + lane * 8;
  *(u16x8*)dst = hv;
  *(u16x8*)(dst + 512) = lv;
}

//============ Main: 16 samples/block, 16 waves, MFMA (act hi, wt hi+lo) =====
__global__ __launch_bounds__(NTH, 8)
void pcf_mfma(const float* __restrict__ ua, const float* __restrict__ ub,
              const float* __restrict__ alog, const float* __restrict__ W1,
              const float* __restrict__ b1, const float* __restrict__ b2,
              const float* __restrict__ c1, const float* __restrict__ c2,
              const float* __restrict__ c3,
              const unsigned short* __restrict__ wt, float* __restrict__ out)
{
  __shared__ unsigned short sAhi[16 * KP];   // 8448 B
  __shared__ unsigned short sBhi[16 * KP];   // 8448 B
  __shared__ float sBL[SPB * 64];            // 4096 B
  __shared__ float sVals[SPB * 64];          // 4096 B  rank scratch (per sample)
  __shared__ float sSelE[SPB * 8];           // 512 B   selected exps (per sample)
  __shared__ int   sSelA[SPB * 5];
  __shared__ float sLpA[SPB];

  const int t    = threadIdx.x;
  const int lane = t & 63;
  const int wv   = t >> 6;                   // 0..15
  const int ln15 = lane & 15;
  const int quad = lane >> 4;
  const int bbase = blockIdx.x * SPB;

  //===== Hoist: beta Gumbel perturbation (needed only after 5 barriers) =====
  float gb;
  {
    int b = bbase + wv;
    float u = ub[(size_t)b * 64 + lane];
    gb = -logf(-logf(fmaxf(u, 1e-10f)));
  }

  //===== Phase A: alpha top-5 + PL (1 sample per wave) =====
  {
    float la = alog[lane];
    float ea = expf(la);
    float Za = waveSum(ea);
    int b = bbase + wv;
    float u = ua[(size_t)b * 64 + lane];
    float ga = -logf(-logf(fmaxf(u, 1e-10f)));
    float lp = selectAndPL(la, ea, Za, ga, out + (size_t)b * 128, lane,
                           &sVals[wv * 64], &sSelE[wv * 8], &sSelA[wv * 5]);
    if (lane == 0) sLpA[wv] = lp;
  }
  __syncthreads();

  //===== Phase H: h[s][0..127] = silu(b1 + sum 5 W1 rows) -> sAhi =====
  {
    int s = wv;                 // sample = wave
    int j = lane * 2;           // cols j, j+1
    const int rows[5] = { sSelA[s * 5 + 0], sSelA[s * 5 + 1], sSelA[s * 5 + 2],
                          sSelA[s * 5 + 3], sSelA[s * 5 + 4] };
    float2 a = *(const float2*)(b1 + j);
#pragma unroll
    for (int r = 0; r < 5; ++r) {
      float2 w = *(const float2*)(W1 + (size_t)rows[r] * 128 + j);
      a.x += w.x; a.y += w.y;
    }
    unsigned h0 = bround(siluf(a.x));
    unsigned h1 = bround(siluf(a.y));
    *(unsigned*)&sAhi[s * KP + j] = h0 | (h1 << 16);
  }
  __syncthreads();

  //===== GEMM1: ctx(16x64) = h @ W2 + b2  (K=128, waves 0-3) =====
  if (wv < 4) {
    f32x4 acc = {0.f, 0.f, 0.f, 0.f};
#pragma unroll
    for (int ks = 0; ks < 4; ++ks) {
      int ko = ks * 32 + quad * 8;
      s16x8 ah = *(const s16x8*)&sAhi[ln15 * KP + ko];
      const unsigned short* tsb = wt + OFF_W2 + (size_t)(wv * 4 + ks) * 1024;
      s16x8 bh = ((const s16x8*)tsb)[lane];
      s16x8 bl = ((const s16x8*)(tsb + 512))[lane];
      acc = MFMA16(ah, bh, acc, 0, 0, 0);
      acc = MFMA16(ah, bl, acc, 0, 0, 0);
    }
    int col = wv * 16 + ln15;
    float bias = b2[col];
#pragma unroll
    for (int r = 0; r < 4; ++r)
      sBhi[(quad * 4 + r) * KP + col] = bround(acc[r] + bias);
  }
  __syncthreads();

  //===== GEMM2: z1(16x256) = silu(ctx @ V1[64:,:] + c1)  (K=64, 1 tile/wave) =====
  {
    f32x4 acc = {0.f, 0.f, 0.f, 0.f};
#pragma unroll
    for (int ks = 0; ks < 2; ++ks) {
      int ko = ks * 32 + quad * 8;
      s16x8 ah = *(const s16x8*)&sBhi[ln15 * KP + ko];
      const unsigned short* tsb = wt + OFF_V1 + (size_t)(wv * 2 + ks) * 1024;
      s16x8 bh = ((const s16x8*)tsb)[lane];
      s16x8 bl = ((const s16x8*)(tsb + 512))[lane];
      acc = MFMA16(ah, bh, acc, 0, 0, 0);
      acc = MFMA16(ah, bl, acc, 0, 0, 0);
    }
    int col = wv * 16 + ln15;
    float bias = c1[col];
#pragma unroll
    for (int r = 0; r < 4; ++r)
      sAhi[(quad * 4 + r) * KP + col] = bround(siluf(acc[r] + bias));
  }
  __syncthreads();

  //===== GEMM3: z2(16x256) = silu(z1 @ V2 + c2)  (K=256, 1 tile/wave) =====
  {
    f32x4 acc = {0.f, 0.f, 0.f, 0.f};
#pragma unroll 4
    for (int ks = 0; ks < 8; ++ks) {
      int ko = ks * 32 + quad * 8;
      s16x8 ah = *(const s16x8*)&sAhi[ln15 * KP + ko];
      const unsigned short* tsb = wt + OFF_V2 + (size_t)(wv * 8 + ks) * 1024;
      s16x8 bh = ((const s16x8*)tsb)[lane];
      s16x8 bl = ((const s16x8*)(tsb + 512))[lane];
      acc = MFMA16(ah, bh, acc, 0, 0, 0);
      acc = MFMA16(ah, bl, acc, 0, 0, 0);
    }
    int col = wv * 16 + ln15;
    float bias = c2[col];
#pragma unroll
    for (int r = 0; r < 4; ++r)
      sBhi[(quad * 4 + r) * KP + col] = bround(siluf(acc[r] + bias));
  }
  __syncthreads();

  //===== GEMM4: beta_logits(16x64) = z2 @ V3 + c3  (K=256, waves 0-3) =====
  if (wv < 4) {
    f32x4 acc = {0.f, 0.f, 0.f, 0.f};
#pragma unroll
    for (int ks = 0; ks < 8; ++ks) {
      int ko = ks * 32 + quad * 8;
      s16x8 ah = *(const s16x8*)&sBhi[ln15 * KP + ko];
      const unsigned short* tsb = wt + OFF_V3 + (size_t)(wv * 8 + ks) * 1024;
      s16x8 bh = ((const s16x8*)tsb)[lane];
      s16x8 bl = ((const s16x8*)(tsb + 512))[lane];
      acc = MFMA16(ah, bh, acc, 0, 0, 0);
      acc = MFMA16(ah, bl, acc, 0, 0, 0);
    }
    int col = wv * 16 + ln15;
    float bias = c3[col];
#pragma unroll
    for (int r = 0; r < 4; ++r)
      sBL[(quad * 4 + r) * 64 + col] = acc[r] + bias;
  }
  __syncthreads();

  //===== Phase B: beta top-5 + PL (1 sample per wave, hoisted Gumbel) =====
  {
    int b = bbase + wv;
    float blv = sBL[wv * 64 + lane];
    float eb = expf(blv);
    float Zb = waveSum(eb);
    float lp = selectAndPL(blv, eb, Zb, gb,
                           out + (size_t)b * 128 + 64, lane,
                           &sVals[wv * 64], &sSelE[wv * 8], nullptr);
    if (lane == 0)
      out[(size_t)8192 * 128 + b] = sLpA[wv] + lp;
  }
}

//================= Fallback (R4-style kernel, no ws needed) =================
#define SPB4 4
__global__ __launch_bounds__(256, 8)
void pcf_small(const float* __restrict__ ua, const float* __restrict__ ub,
               const float* __restrict__ alog, const float* __restrict__ W1,
               const float* __restrict__ b1, const float* __restrict__ W2,
               const float* __restrict__ b2, const float* __restrict__ V1,
               const float* __restrict__ c1, const float* __restrict__ V2,
               const float* __restrict__ c2, const float* __restrict__ V3,
               const float* __restrict__ c3, float* __restrict__ out)
{
  __shared__ float sA[SPB4 * 256];
  __shared__ float sB[SPB4 * 256];
  __shared__ float sP[4 * 256];
  __shared__ float sVals[4 * 64];
  __shared__ float sSelE[4 * 8];
  __shared__ int   sSelA[SPB4 * 5];
  __shared__ float sLpA[SPB4];

  const int t    = threadIdx.x;
  const int lane = t & 63;
  const int wv   = t >> 6;
  const int bbase = blockIdx.x * SPB4;

  float* sValsRow = &sVals[wv * 64];
  float* sSelERow = &sSelE[wv * 8];

  {
    float la = alog[lane];
    float ea = expf(la);
    float Za = waveSum(ea);
    int b = bbase + wv;
    float u = ua[(size_t)b * 64 + lane];
    float g = -logf(-logf(fmaxf(u, 1e-10f)));
    float lp = selectAndPL(la, ea, Za, g, out + (size_t)b * 128, lane,
                           sValsRow, sSelERow, &sSelA[wv * 5]);
    if (lane == 0) sLpA[wv] = lp;
  }
  __syncthreads();
  {
    int s = wv;
    int i0 = sSelA[s * 5 + 0], i1 = sSelA[s * 5 + 1], i2 = sSelA[s * 5 + 2];
    int i3 = sSelA[s * 5 + 3], i4 = sSelA[s * 5 + 4];
#pragma unroll
    for (int jh = 0; jh < 2; ++jh) {
      int j = lane + jh * 64;
      float acc = b1[j] + W1[i0 * 128 + j] + W1[i1 * 128 + j]
                + W1[i2 * 128 + j] + W1[i3 * 128 + j] + W1[i4 * 128 + j];
      sA[s * 128 + j] = siluf(acc);
    }
  }
  __syncthreads();
  {
    float acc[SPB4] = {};
    const int kb = 32 * wv;
#pragma unroll 2
    for (int m = 0; m < 8; ++m) {
      int k0 = kb + 4 * m;
      float w0 = W2[(k0 + 0) * 64 + lane];
      float w1 = W2[(k0 + 1) * 64 + lane];
      float w2 = W2[(k0 + 2) * 64 + lane];
      float w3 = W2[(k0 + 3) * 64 + lane];
#pragma unroll
      for (int s = 0; s < SPB4; ++s) {
        float4 x = *(float4*)&sA[s * 128 + k0];
        acc[s] += x.x * w0 + x.y * w1 + x.z * w2 + x.w * w3;
      }
    }
#pragma unroll
    for (int s = 0; s < SPB4; ++s) sP[wv * 256 + s * 64 + lane] = acc[s];
  }
  __syncthreads();
  {
    int o = t;
    float v = b2[o & 63] + sP[o] + sP[256 + o] + sP[512 + o] + sP[768 + o];
    sB[o] = v;
  }
  __syncthreads();
  {
    const int c = 64 * wv + lane;
    float acc[SPB4];
    float cb = c1[c];
#pragma unroll
    for (int s = 0; s < SPB4; ++s) acc[s] = cb;
    const float* wp = V1 + (size_t)64 * 256 + c;
#pragma unroll 4
    for (int m = 0; m < 16; ++m) {
      int k0 = 4 * m;
      float w0 = wp[(k0 + 0) * 256];
      float w1 = wp[(k0 + 1) * 256];
      float w2 = wp[(k0 + 2) * 256];
      float w3 = wp[(k0 + 3) * 256];
#pragma unroll
      for (int s = 0; s < SPB4; ++s) {
        float4 x = *(float4*)&sB[s * 64 + k0];
        acc[s] += x.x * w0 + x.y * w1 + x.z * w2 + x.w * w3;
      }
    }
#pragma unroll
    for (int s = 0; s < SPB4; ++s) sA[s * 256 + c] = siluf(acc[s]);
  }
  __syncthreads();
  {
    const int c = 64 * wv + lane;
    float acc[SPB4];
    float cb = c2[c];
#pragma unroll
    for (int s = 0; s < SPB4; ++s) acc[s] = cb;
    const float* wp = V2 + c;
#pragma unroll 4
    for (int m = 0; m < 64; ++m) {
      int k0 = 4 * m;
      float w0 = wp[(size_t)(k0 + 0) * 256];
      float w1 = wp[(size_t)(k0 + 1) * 256];
      float w2 = wp[(size_t)(k0 + 2) * 256];
      float w3 = wp[(size_t)(k0 + 3) * 256];
#pragma unroll
      for (int s = 0; s < SPB4; ++s) {
        float4 x = *(float4*)&sA[s * 256 + k0];
        acc[s] += x.x * w0 + x.y * w1 + x.z * w2 + x.w * w3;
      }
    }
#pragma unroll
    for (int s = 0; s < SPB4; ++s) sB[s * 256 + c] = siluf(acc[s]);
  }
  __syncthreads();
  {
    float acc[SPB4] = {};
    const int kb = 64 * wv;
#pragma unroll 4
    for (int m = 0; m < 16; ++m) {
      int k0 = kb + 4 * m;
      float w0 = V3[(k0 + 0) * 64 + lane];
      float w1 = V3[(k0 + 1) * 64 + lane];
      float w2 = V3[(k0 + 2) * 64 + lane];
      float w3 = V3[(k0 + 3) * 64 + lane];
#pragma unroll
      for (int s = 0; s < SPB4; ++s) {
        float4 x = *(float4*)&sB[s * 256 + k0];
        acc[s] += x.x * w0 + x.y * w1 + x.z * w2 + x.w * w3;
      }
    }
#pragma unroll
    for (int s = 0; s < SPB4; ++s) sP[wv * 256 + s * 64 + lane] = acc[s];
  }
  __syncthreads();
  {
    int b = bbase + wv;
    float blv = c3[lane] + sP[wv * 64 + lane] + sP[256 + wv * 64 + lane]
              + sP[512 + wv * 64 + lane] + sP[768 + wv * 64 + lane];
    float eb = expf(blv);
    float Zb = waveSum(eb);
    float u = ub[(size_t)b * 64 + lane];
    float g = -logf(-logf(fmaxf(u, 1e-10f)));
    float lp = selectAndPL(blv, eb, Zb, g, out + (size_t)b * 128 + 64, lane,
                           sValsRow, sSelERow, nullptr);
    if (lane == 0)
      out[(size_t)8192 * 128 + b] = sLpA[wv] + lp;
  }
}

extern "C" void kernel_launch(void* const* d_in, const int* in_sizes, int n_in,
                              void* d_out, int out_size, void* d_ws, size_t ws_size,
                              hipStream_t stream) {
  const float* ua   = (const float*)d_in[0];
  const float* ub   = (const float*)d_in[1];
  const float* alog = (const float*)d_in[2];
  const float* W1   = (const float*)d_in[3];
  const float* b1   = (const float*)d_in[4];
  const float* W2   = (const float*)d_in[5];
  const float* b2   = (const float*)d_in[6];
  const float* V1   = (const float*)d_in[7];
  const float* c1   = (const float*)d_in[8];
  const float* V2   = (const float*)d_in[9];
  const float* c2   = (const float*)d_in[10];
  const float* V3   = (const float*)d_in[11];
  const float* c3   = (const float*)d_in[12];
  float* out = (float*)d_out;

  if (ws_size >= (size_t)WS_USHORTS * 2) {
    unsigned short* wt = (unsigned short*)d_ws;
    pcf_prep<<<dim3(52), dim3(256), 0, stream>>>(W2, V1, V2, V3, wt);
    pcf_mfma<<<dim3(8192 / SPB), dim3(NTH), 0, stream>>>(
        ua, ub, alog, W1, b1, b2, c1, c2, c3, wt, out);
  } else {
    pcf_small<<<dim3(8192 / SPB4), dim3(256), 0, stream>>>(
        ua, ub, alog, W1, b1, W2, b2, V1, c1, V2, c2, V3, c3, out);
  }
}

// Round 13
// 105.254 us; speedup vs baseline: 1.1244x; 1.0070x over previous
//
#include <hip/hip_runtime.h>
#include <math.h>

#define NTH 1024                    // 16 waves per block
#define KP 264                      // LDS row stride (ushorts), padded
#define SPB 16                      // samples per block (fills M=16 MFMA tiles)
#define OFF_W2 0                    // 4 tiles x 4 ksteps
#define OFF_V1 16384                // 16 x 2
#define OFF_V2 49152                // 16 x 8
#define OFF_V3 180224               // 4 x 8
#define WS_USHORTS 212992
#define MFMA16 __builtin_amdgcn_mfma_f32_16x16x32_bf16

typedef __attribute__((ext_vector_type(8))) short s16x8;
typedef __attribute__((ext_vector_type(8))) unsigned short u16x8;
typedef __attribute__((ext_vector_type(4))) float f32x4;

__device__ __forceinline__ float waveSum(float v) {
#pragma unroll
  for (int off = 32; off; off >>= 1) v += __shfl_xor(v, off, 64);
  return v;
}

// Fast silu: __expf error ~1e-7 rel; output is bf16-rounded (2^-9) anyway.
__device__ __forceinline__ float siluf(float x) { return x / (1.0f + __expf(-x)); }

// Round fp32 -> bf16 (RNE), return bits.
__device__ __forceinline__ unsigned short bround(float x) {
  unsigned u = __float_as_uint(x);
  return (unsigned short)((u + 0x7FFFu + ((u >> 16) & 1u)) >> 16);
}

// Split fp32 into bf16 hi + bf16 lo (round-to-nearest-even).
__device__ __forceinline__ void bsplit(float x, unsigned short& h, unsigned short& l) {
  unsigned u = __float_as_uint(x);
  unsigned hb = (u + 0x7FFFu + ((u >> 16) & 1u)) >> 16;
  float hf = __uint_as_float(hb << 16);
  float lf = x - hf;
  unsigned ul = __float_as_uint(lf);
  unsigned lb = (ul + 0x7FFFu + ((ul >> 16) & 1u)) >> 16;
  h = (unsigned short)hb; l = (unsigned short)lb;
}

// permSum is symmetric in (se0..se4): it sums over all 120 orderings.
// rcpf: 1e-7 rel error on S -> log_probs error ~1e-7 vs 0.64 threshold.
__device__ __forceinline__ float permSum(const float se0, const float se1,
                                         const float se2, const float se3,
                                         const float se4, float Z, int lane) {
  float psum = 0.0f;
#pragma unroll
  for (int pp = 0; pp < 2; ++pp) {
    int p = lane + pp * 64;
    if (p < 120) {
      int rem = p;
      unsigned avail = 0x43210u;
      float c = 0.0f;
      float prod = Z;
#pragma unroll
      for (int j = 0; j < 4; ++j) {
        const int fct = (j == 0) ? 24 : (j == 1) ? 6 : (j == 2) ? 2 : 1;
        int q = rem / fct; rem -= q * fct;
        int sh = q * 4;
        int dg = (avail >> sh) & 0xF;
        avail = (avail & ((1u << sh) - 1u)) | ((avail >> (sh + 4)) << sh);
        float ev = (dg == 0) ? se0 : (dg == 1) ? se1 : (dg == 2) ? se2
                 : (dg == 3) ? se3 : se4;
        c += ev;
        prod *= (Z - c);
      }
      psum += __builtin_amdgcn_rcpf(prod);
    }
  }
  return psum;
}

// Rank-based Gumbel top-5 + exact PL log-prob; g = precomputed perturbation
// (computed with PRECISE logf — it determines selection). Tie-break (equal v
// -> lower index) matches jax.lax.top_k. LDS rows are per-sample; same-wave
// DS ordering makes this barrier-free. sSelERow: [0..4]=exps, [8..12]=logits.
__device__ __forceinline__ float selectAndPL(float lv, float ev, float Z,
                                             float g,
                                             float* __restrict__ gout,
                                             int lane,
                                             float* __restrict__ sValsRow,
                                             float* __restrict__ sSelERow,
                                             int* __restrict__ selIdxRow) {
  float v = lv + g;
  sValsRow[lane] = v;
  int rank = 0;
#pragma unroll
  for (int j = 0; j < 16; ++j) {
    float4 w = *(const float4*)&sValsRow[j * 4];
    int base = j * 4;
    rank += (w.x > v || (w.x == v && base + 0 < lane)) ? 1 : 0;
    rank += (w.y > v || (w.y == v && base + 1 < lane)) ? 1 : 0;
    rank += (w.z > v || (w.z == v && base + 2 < lane)) ? 1 : 0;
    rank += (w.w > v || (w.w == v && base + 3 < lane)) ? 1 : 0;
  }
  bool sel = rank < 5;
  gout[lane] = sel ? 1.0f : 0.0f;
  if (sel) {
    sSelERow[rank] = ev;
    sSelERow[8 + rank] = lv;
    if (selIdxRow) selIdxRow[rank] = lane;
  }
  float se0 = sSelERow[0], se1 = sSelERow[1], se2 = sSelERow[2],
        se3 = sSelERow[3], se4 = sSelERow[4];
  float sl = sSelERow[8] + sSelERow[9] + sSelERow[10] + sSelERow[11]
           + sSelERow[12];
  float S = waveSum(permSum(se0, se1, se2, se3, se4, Z, lane));
  return sl + __logf(S);
}

//============ Prep: tile + split weights into fragment order ============
__global__ __launch_bounds__(256)
void pcf_prep(const float* __restrict__ W2, const float* __restrict__ V1,
              const float* __restrict__ V2, const float* __restrict__ V3,
              unsigned short* __restrict__ ws)
{
  int tid = blockIdx.x * 256 + threadIdx.x;
  const float* src; int N, Ks, dstoff, r;
  if (tid < 1024)       { src = W2;            N = 64;  Ks = 4; dstoff = OFF_W2; r = tid; }
  else if (tid < 3072)  { src = V1 + 64 * 256; N = 256; Ks = 2; dstoff = OFF_V1; r = tid - 1024; }
  else if (tid < 11264) { src = V2;            N = 256; Ks = 8; dstoff = OFF_V2; r = tid - 3072; }
  else                  { src = V3;            N = 64;  Ks = 8; dstoff = OFF_V3; r = tid - 11264; }
  int lane = r & 63, ts = r >> 6;
  int ks = ts % Ks, ct = ts / Ks;
  int n = ct * 16 + (lane & 15);
  int k0 = ks * 32 + (lane >> 4) * 8;
  u16x8 hv, lv;
#pragma unroll
  for (int j = 0; j < 8; ++j) {
    float x = src[(size_t)(k0 + j) * N + n];
    unsigned short h, l;
    bsplit(x, h, l);
    hv[j] = h; lv[j] = l;
  }
  unsigned short* dst = ws + dstoff + (size_t)ts * 1024 + lane * 8;
  *(u16x8*)dst = hv;
  *(u16x8*)(dst + 512) = lv;
}

//============ Main: 16 samples/block, 16 waves, MFMA (act hi, wt hi+lo) =====
__global__ __launch_bounds__(NTH, 8)
void pcf_mfma(const float* __restrict__ ua, const float* __restrict__ ub,
              const float* __restrict__ alog, const float* __restrict__ W1,
              const float* __restrict__ b1, const float* __restrict__ b2,
              const float* __restrict__ c1, const float* __restrict__ c2,
              const float* __restrict__ c3,
              const unsigned short* __restrict__ wt, float* __restrict__ out)
{
  __shared__ unsigned short sAhi[16 * KP];   // 8448 B
  __shared__ unsigned short sBhi[16 * KP];   // 8448 B
  __shared__ float sBL[SPB * 64];            // 4096 B
  __shared__ float sVals[SPB * 64];          // 4096 B  rank scratch (per sample)
  __shared__ float sSelE[SPB * 16];          // 1024 B  selected exps+logits
  __shared__ int   sSelA[SPB * 5];
  __shared__ float sLpA[SPB];

  const int t    = threadIdx.x;
  const int lane = t & 63;
  const int wv   = t >> 6;                   // 0..15
  const int ln15 = lane & 15;
  const int quad = lane >> 4;
  const int bbase = blockIdx.x * SPB;

  //===== Hoist: beta Gumbel perturbation (needed only after 5 barriers) =====
  float gb;
  {
    int b = bbase + wv;
    float u = ub[(size_t)b * 64 + lane];
    gb = -logf(-logf(fmaxf(u, 1e-10f)));     // precise: selection path
  }

  //===== Phase A: alpha top-5 + PL (1 sample per wave) =====
  {
    float la = alog[lane];
    float ea = __expf(la);
    float Za = waveSum(ea);
    int b = bbase + wv;
    float u = ua[(size_t)b * 64 + lane];
    float ga = -logf(-logf(fmaxf(u, 1e-10f)));  // precise: selection path
    float lp = selectAndPL(la, ea, Za, ga, out + (size_t)b * 128, lane,
                           &sVals[wv * 64], &sSelE[wv * 16], &sSelA[wv * 5]);
    if (lane == 0) sLpA[wv] = lp;
  }
  __syncthreads();

  //===== Phase H: h[s][0..127] = silu(b1 + sum 5 W1 rows) -> sAhi =====
  {
    int s = wv;                 // sample = wave
    int j = lane * 2;           // cols j, j+1
    const int rows[5] = { sSelA[s * 5 + 0], sSelA[s * 5 + 1], sSelA[s * 5 + 2],
                          sSelA[s * 5 + 3], sSelA[s * 5 + 4] };
    float2 a = *(const float2*)(b1 + j);
#pragma unroll
    for (int r = 0; r < 5; ++r) {
      float2 w = *(const float2*)(W1 + (size_t)rows[r] * 128 + j);
      a.x += w.x; a.y += w.y;
    }
    unsigned h0 = bround(siluf(a.x));
    unsigned h1 = bround(siluf(a.y));
    *(unsigned*)&sAhi[s * KP + j] = h0 | (h1 << 16);
  }
  __syncthreads();

  //===== GEMM1: ctx(16x64) = h @ W2 + b2  (K=128, waves 0-3) =====
  if (wv < 4) {
    f32x4 acc = {0.f, 0.f, 0.f, 0.f};
#pragma unroll
    for (int ks = 0; ks < 4; ++ks) {
      int ko = ks * 32 + quad * 8;
      s16x8 ah = *(const s16x8*)&sAhi[ln15 * KP + ko];
      const unsigned short* tsb = wt + OFF_W2 + (size_t)(wv * 4 + ks) * 1024;
      s16x8 bh = ((const s16x8*)tsb)[lane];
      s16x8 bl = ((const s16x8*)(tsb + 512))[lane];
      acc = MFMA16(ah, bh, acc, 0, 0, 0);
      acc = MFMA16(ah, bl, acc, 0, 0, 0);
    }
    int col = wv * 16 + ln15;
    float bias = b2[col];
#pragma unroll
    for (int r = 0; r < 4; ++r)
      sBhi[(quad * 4 + r) * KP + col] = bround(acc[r] + bias);
  }
  __syncthreads();

  //===== GEMM2: z1(16x256) = silu(ctx @ V1[64:,:] + c1)  (K=64, 1 tile/wave) =====
  {
    f32x4 acc = {0.f, 0.f, 0.f, 0.f};
#pragma unroll
    for (int ks = 0; ks < 2; ++ks) {
      int ko = ks * 32 + quad * 8;
      s16x8 ah = *(const s16x8*)&sBhi[ln15 * KP + ko];
      const unsigned short* tsb = wt + OFF_V1 + (size_t)(wv * 2 + ks) * 1024;
      s16x8 bh = ((const s16x8*)tsb)[lane];
      s16x8 bl = ((const s16x8*)(tsb + 512))[lane];
      acc = MFMA16(ah, bh, acc, 0, 0, 0);
      acc = MFMA16(ah, bl, acc, 0, 0, 0);
    }
    int col = wv * 16 + ln15;
    float bias = c1[col];
#pragma unroll
    for (int r = 0; r < 4; ++r)
      sAhi[(quad * 4 + r) * KP + col] = bround(siluf(acc[r] + bias));
  }
  __syncthreads();

  //===== GEMM3: z2(16x256) = silu(z1 @ V2 + c2)  (K=256, 1 tile/wave) =====
  {
    f32x4 acc = {0.f, 0.f, 0.f, 0.f};
#pragma unroll 4
    for (int ks = 0; ks < 8; ++ks) {
      int ko = ks * 32 + quad * 8;
      s16x8 ah = *(const s16x8*)&sAhi[ln15 * KP + ko];
      const unsigned short* tsb = wt + OFF_V2 + (size_t)(wv * 8 + ks) * 1024;
      s16x8 bh = ((const s16x8*)tsb)[lane];
      s16x8 bl = ((const s16x8*)(tsb + 512))[lane];
      acc = MFMA16(ah, bh, acc, 0, 0, 0);
      acc = MFMA16(ah, bl, acc, 0, 0, 0);
    }
    int col = wv * 16 + ln15;
    float bias = c2[col];
#pragma unroll
    for (int r = 0; r < 4; ++r)
      sBhi[(quad * 4 + r) * KP + col] = bround(siluf(acc[r] + bias));
  }
  __syncthreads();

  //===== GEMM4: beta_logits(16x64) = z2 @ V3 + c3  (K=256, waves 0-3) =====
  if (wv < 4) {
    f32x4 acc = {0.f, 0.f, 0.f, 0.f};
#pragma unroll
    for (int ks = 0; ks < 8; ++ks) {
      int ko = ks * 32 + quad * 8;
      s16x8 ah = *(const s16x8*)&sBhi[ln15 * KP + ko];
      const unsigned short* tsb = wt + OFF_V3 + (size_t)(wv * 8 + ks) * 1024;
      s16x8 bh = ((const s16x8*)tsb)[lane];
      s16x8 bl = ((const s16x8*)(tsb + 512))[lane];
      acc = MFMA16(ah, bh, acc, 0, 0, 0);
      acc = MFMA16(ah, bl, acc, 0, 0, 0);
    }
    int col = wv * 16 + ln15;
    float bias = c3[col];
#pragma unroll
    for (int r = 0; r < 4; ++r)
      sBL[(quad * 4 + r) * 64 + col] = acc[r] + bias;
  }
  __syncthreads();

  //===== Phase B: beta top-5 + PL (1 sample per wave, hoisted Gumbel) =====
  {
    int b = bbase + wv;
    float blv = sBL[wv * 64 + lane];
    float eb = __expf(blv);
    float Zb = waveSum(eb);
    float lp = selectAndPL(blv, eb, Zb, gb,
                           out + (size_t)b * 128 + 64, lane,
                           &sVals[wv * 64], &sSelE[wv * 16], nullptr);
    if (lane == 0)
      out[(size_t)8192 * 128 + b] = sLpA[wv] + lp;
  }
}

//================= Fallback (R4-style kernel, no ws needed) =================
#define SPB4 4
__global__ __launch_bounds__(256, 8)
void pcf_small(const float* __restrict__ ua, const float* __restrict__ ub,
               const float* __restrict__ alog, const float* __restrict__ W1,
               const float* __restrict__ b1, const float* __restrict__ W2,
               const float* __restrict__ b2, const float* __restrict__ V1,
               const float* __restrict__ c1, const float* __restrict__ V2,
               const float* __restrict__ c2, const float* __restrict__ V3,
               const float* __restrict__ c3, float* __restrict__ out)
{
  __shared__ float sA[SPB4 * 256];
  __shared__ float sB[SPB4 * 256];
  __shared__ float sP[4 * 256];
  __shared__ float sVals[4 * 64];
  __shared__ float sSelE[4 * 16];
  __shared__ int   sSelA[SPB4 * 5];
  __shared__ float sLpA[SPB4];

  const int t    = threadIdx.x;
  const int lane = t & 63;
  const int wv   = t >> 6;
  const int bbase = blockIdx.x * SPB4;

  float* sValsRow = &sVals[wv * 64];
  float* sSelERow = &sSelE[wv * 16];

  {
    float la = alog[lane];
    float ea = __expf(la);
    float Za = waveSum(ea);
    int b = bbase + wv;
    float u = ua[(size_t)b * 64 + lane];
    float g = -logf(-logf(fmaxf(u, 1e-10f)));
    float lp = selectAndPL(la, ea, Za, g, out + (size_t)b * 128, lane,
                           sValsRow, sSelERow, &sSelA[wv * 5]);
    if (lane == 0) sLpA[wv] = lp;
  }
  __syncthreads();
  {
    int s = wv;
    int i0 = sSelA[s * 5 + 0], i1 = sSelA[s * 5 + 1], i2 = sSelA[s * 5 + 2];
    int i3 = sSelA[s * 5 + 3], i4 = sSelA[s * 5 + 4];
#pragma unroll
    for (int jh = 0; jh < 2; ++jh) {
      int j = lane + jh * 64;
      float acc = b1[j] + W1[i0 * 128 + j] + W1[i1 * 128 + j]
                + W1[i2 * 128 + j] + W1[i3 * 128 + j] + W1[i4 * 128 + j];
      sA[s * 128 + j] = siluf(acc);
    }
  }
  __syncthreads();
  {
    float acc[SPB4] = {};
    const int kb = 32 * wv;
#pragma unroll 2
    for (int m = 0; m < 8; ++m) {
      int k0 = kb + 4 * m;
      float w0 = W2[(k0 + 0) * 64 + lane];
      float w1 = W2[(k0 + 1) * 64 + lane];
      float w2 = W2[(k0 + 2) * 64 + lane];
      float w3 = W2[(k0 + 3) * 64 + lane];
#pragma unroll
      for (int s = 0; s < SPB4; ++s) {
        float4 x = *(float4*)&sA[s * 128 + k0];
        acc[s] += x.x * w0 + x.y * w1 + x.z * w2 + x.w * w3;
      }
    }
#pragma unroll
    for (int s = 0; s < SPB4; ++s) sP[wv * 256 + s * 64 + lane] = acc[s];
  }
  __syncthreads();
  {
    int o = t;
    float v = b2[o & 63] + sP[o] + sP[256 + o] + sP[512 + o] + sP[768 + o];
    sB[o] = v;
  }
  __syncthreads();
  {
    const int c = 64 * wv + lane;
    float acc[SPB4];
    float cb = c1[c];
#pragma unroll
    for (int s = 0; s < SPB4; ++s) acc[s] = cb;
    const float* wp = V1 + (size_t)64 * 256 + c;
#pragma unroll 4
    for (int m = 0; m < 16; ++m) {
      int k0 = 4 * m;
      float w0 = wp[(k0 + 0) * 256];
      float w1 = wp[(k0 + 1) * 256];
      float w2 = wp[(k0 + 2) * 256];
      float w3 = wp[(k0 + 3) * 256];
#pragma unroll
      for (int s = 0; s < SPB4; ++s) {
        float4 x = *(float4*)&sB[s * 64 + k0];
        acc[s] += x.x * w0 + x.y * w1 + x.z * w2 + x.w * w3;
      }
    }
#pragma unroll
    for (int s = 0; s < SPB4; ++s) sA[s * 256 + c] = siluf(acc[s]);
  }
  __syncthreads();
  {
    const int c = 64 * wv + lane;
    float acc[SPB4];
    float cb = c2[c];
#pragma unroll
    for (int s = 0; s < SPB4; ++s) acc[s] = cb;
    const float* wp = V2 + c;
#pragma unroll 4
    for (int m = 0; m < 64; ++m) {
      int k0 = 4 * m;
      float w0 = wp[(size_t)(k0 + 0) * 256];
      float w1 = wp[(size_t)(k0 + 1) * 256];
      float w2 = wp[(size_t)(k0 + 2) * 256];
      float w3 = wp[(size_t)(k0 + 3) * 256];
#pragma unroll
      for (int s = 0; s < SPB4; ++s) {
        float4 x = *(float4*)&sA[s * 256 + k0];
        acc[s] += x.x * w0 + x.y * w1 + x.z * w2 + x.w * w3;
      }
    }
#pragma unroll
    for (int s = 0; s < SPB4; ++s) sB[s * 256 + c] = siluf(acc[s]);
  }
  __syncthreads();
  {
    float acc[SPB4] = {};
    const int kb = 64 * wv;
#pragma unroll 4
    for (int m = 0; m < 16; ++m) {
      int k0 = kb + 4 * m;
      float w0 = V3[(k0 + 0) * 64 + lane];
      float w1 = V3[(k0 + 1) * 64 + lane];
      float w2 = V3[(k0 + 2) * 64 + lane];
      float w3 = V3[(k0 + 3) * 64 + lane];
#pragma unroll
      for (int s = 0; s < SPB4; ++s) {
        float4 x = *(float4*)&sB[s * 256 + k0];
        acc[s] += x.x * w0 + x.y * w1 + x.z * w2 + x.w * w3;
      }
    }
#pragma unroll
    for (int s = 0; s < SPB4; ++s) sP[wv * 256 + s * 64 + lane] = acc[s];
  }
  __syncthreads();
  {
    int b = bbase + wv;
    float blv = c3[lane] + sP[wv * 64 + lane] + sP[256 + wv * 64 + lane]
              + sP[512 + wv * 64 + lane] + sP[768 + wv * 64 + lane];
    float eb = __expf(blv);
    float Zb = waveSum(eb);
    float u = ub[(size_t)b * 64 + lane];
    float g = -logf(-logf(fmaxf(u, 1e-10f)));
    float lp = selectAndPL(blv, eb, Zb, g, out + (size_t)b * 128 + 64, lane,
                           sValsRow, sSelERow, nullptr);
    if (lane == 0)
      out[(size_t)8192 * 128 + b] = sLpA[wv] + lp;
  }
}

extern "C" void kernel_launch(void* const* d_in, const int* in_sizes, int n_in,
                              void* d_out, int out_size, void* d_ws, size_t ws_size,
                              hipStream_t stream) {
  const float* ua   = (const float*)d_in[0];
  const float* ub   = (const float*)d_in[1];
  const float* alog = (const float*)d_in[2];
  const float* W1   = (const float*)d_in[3];
  const float* b1   = (const float*)d_in[4];
  const float* W2   = (const float*)d_in[5];
  const float* b2   = (const float*)d_in[6];
  const float* V1   = (const float*)d_in[7];
  const float* c1   = (const float*)d_in[8];
  const float* V2   = (const float*)d_in[9];
  const float* c2   = (const float*)d_in[10];
  const float* V3   = (const float*)d_in[11];
  const float* c3   = (const float*)d_in[12];
  float* out = (float*)d_out;

  if (ws_size >= (size_t)WS_USHORTS * 2) {
    unsigned short* wt = (unsigned short*)d_ws;
    pcf_prep<<<dim3(52), dim3(256), 0, stream>>>(W2, V1, V2, V3, wt);
    pcf_mfma<<<dim3(8192 / SPB), dim3(NTH), 0, stream>>>(
        ua, ub, alog, W1, b1, b2, c1, c2, c3, wt, out);
  } else {
    pcf_small<<<dim3(8192 / SPB4), dim3(256), 0, stream>>>(
        ua, ub, alog, W1, b1, W2, b2, V1, c1, V2, c2, V3, c3, out);
  }
}